// Round 9
// baseline (189.266 us; speedup 1.0000x reference)
//
#include <hip/hip_runtime.h>

#define NNODES 40000
#define NEDGES 640000
#define PAD 64
#define NBK 160           // dst-range buckets
#define BNODES 250        // nodes per bucket (160*250 = 40000)
#define SCAP 80           // per-(bucket,wg) slice capacity (mean 25, ~11 sigma)
#define ACHUNK 4000       // edges per buildA WG (160*4000 = 640000)
// IN_F = 128, HID = 128, OUT_F = 64

typedef unsigned int uint32;
typedef unsigned short ushort16;
typedef short bf16x8 __attribute__((ext_vector_type(8)));
typedef float f32x4 __attribute__((ext_vector_type(4)));

// ---------------- bf16 helpers ----------------
static __device__ __forceinline__ ushort16 f2bf(float f) {
    uint32 u = __builtin_bit_cast(uint32, f);
    uint32 r = u + 0x7fffu + ((u >> 16) & 1u);  // RNE
    return (ushort16)(r >> 16);
}
static __device__ __forceinline__ float bf_lo(uint32 u) {
    uint32 t = u << 16;
    return __builtin_bit_cast(float, t);
}
static __device__ __forceinline__ float bf_hi(uint32 u) {
    uint32 t = u & 0xffff0000u;
    return __builtin_bit_cast(float, t);
}

static __device__ __forceinline__ void acc8(float* s, uint4 u) {
    s[0] += bf_lo(u.x); s[1] += bf_hi(u.x);
    s[2] += bf_lo(u.y); s[3] += bf_hi(u.y);
    s[4] += bf_lo(u.z); s[5] += bf_hi(u.z);
    s[6] += bf_lo(u.w); s[7] += bf_hi(u.w);
}

static __device__ __forceinline__ int edge_val(const void* ep, long long idx, int is64) {
    if (is64) return (int)((const long long*)ep)[idx];
    return ((const int*)ep)[idx];
}

static __device__ __forceinline__ int imin(int a, int b) { return a < b ? a : b; }

// ---------------- fused prep + buildA --------------------------------------------------
// blocks [0, 5000):    x -> bf16 row-major (1.28M float4 = 5000*256)
// blocks [5000, 5192): weight packing into MFMA B-fragment order (49152 threads)
// blocks [5192, 5352): buildA wg = b-5192 — SINGLE-PASS radix partition: each WG owns a
//   fixed slice per bucket (SCAP entries), so the slot is known at the LDS-atomic return.
//   No count pass, no global reservation atomics, edge list read exactly once.
__global__ void prep_build_kernel(const float* __restrict__ x, uint32* __restrict__ xbf2,
                                  const float* __restrict__ W1l, const float* __restrict__ W1r,
                                  const float* __restrict__ W2l, const float* __restrict__ W2r,
                                  ushort16* __restrict__ Wfrag1, ushort16* __restrict__ Wfrag2,
                                  const void* __restrict__ edges, const int* __restrict__ e32,
                                  int* __restrict__ bstream, int* __restrict__ wgcnt) {
    __shared__ int lcnt[NBK];
    __shared__ int s_is64;
    int b = blockIdx.x;
    int tid = threadIdx.x;
    if (b < 5000) {
        int i = b * 256 + tid;
        float4 v = ((const float4*)x)[i];
        uint2 o;
        o.x = (uint32)f2bf(v.x) | ((uint32)f2bf(v.y) << 16);
        o.y = (uint32)f2bf(v.z) | ((uint32)f2bf(v.w) << 16);
        ((uint2*)xbf2)[i] = o;
        return;
    }
    if (b < 5192) {
        int i = (b - 5000) * 256 + tid;  // 49152 total
        if (i < 32768) {
            int j = i & 7, lane = (i >> 3) & 63, nt = (i >> 9) & 7, s = (i >> 12) & 3,
                by = i >> 14;
            int k = s * 32 + (lane >> 4) * 8 + j;
            int col = nt * 16 + (lane & 15);
            float v = (by == 0) ? W1l[k * 128 + col] : W1r[k * 128 + col];
            Wfrag1[i] = f2bf(v);
        } else {
            int q = i - 32768;  // 16384
            int j = q & 7, lane = (q >> 3) & 63, nt = (q >> 9) & 7, s = (q >> 12) & 3;
            int k = s * 32 + (lane >> 4) * 8 + j;
            int col = nt * 16 + (lane & 15);
            float v = (col < 64) ? W2l[k * 64 + col] : W2r[k * 64 + (col - 64)];
            Wfrag2[q] = f2bf(v);
        }
        return;
    }
    // ---- buildA ----
    int wg = b - 5192;
    for (int i = tid; i < NBK; i += 256) lcnt[i] = 0;
    if (tid == 0) {
        int any = 0;
        for (int t = 0; t < 64; ++t) any |= e32[2 * t + 1];  // int64 hi-words all zero
        s_is64 = (any == 0) ? 1 : 0;
    }
    __syncthreads();
    int is64 = s_is64;
    int base = wg * ACHUNK;
#pragma unroll
    for (int k = 0; k < (ACHUNK + 255) / 256; ++k) {
        int off = k * 256 + tid;
        if (off < ACHUNK) {
            int e = base + off;
            int d = edge_val(edges, (long long)NEDGES + e, is64);
            int s = edge_val(edges, e, is64);
            int bk = d / BNODES;
            int dloc = d - bk * BNODES;
            int r = atomicAdd(&lcnt[bk], 1);
            if (r < SCAP) bstream[(bk * NBK + wg) * SCAP + r] = (s << 8) | dloc;
        }
    }
    __syncthreads();
    for (int i = tid; i < NBK; i += 256) wgcnt[wg * NBK + i] = imin(lcnt[i], SCAP);
}

// ---------------- buildB: per-bucket LDS regroup -> dense USHORT padded-CSR -----------
// One WG per bucket: sweep the 160 fixed slices (12800 slots), scatter valid entries
// into a 32 KB LDS image (250 nodes x 64 ushort) with LDS atomics, write back densely.
__global__ __launch_bounds__(256) void buildB_kernel(const int* __restrict__ bstream,
                                                     const int* __restrict__ wgcnt,
                                                     int* __restrict__ cnt,
                                                     unsigned short* __restrict__ csr16) {
    __shared__ uint4 img4[BNODES * 8];  // 32000 B (250 x 64 ushort)
    __shared__ int hist[BNODES];
    unsigned short* img = (unsigned short*)img4;
    int tid = threadIdx.x;
    int bk = blockIdx.x;
    for (int i = tid; i < BNODES; i += 256) hist[i] = 0;
    __syncthreads();
    for (int i = tid; i < NBK * SCAP; i += 256) {
        int wg = i / SCAP;
        int r = i - wg * SCAP;
        if (r < wgcnt[wg * NBK + bk]) {
            int u = bstream[(bk * NBK + wg) * SCAP + r];
            int dloc = u & 255;
            int rr = atomicAdd(&hist[dloc], 1);
            if (rr < PAD) img[dloc * PAD + rr] = (unsigned short)(u >> 8);
        }
    }
    __syncthreads();
    uint4* dst = (uint4*)(csr16 + (size_t)bk * BNODES * PAD);
#pragma unroll
    for (int i = tid; i < BNODES * 8; i += 256) dst[i] = img4[i];
    for (int i = tid; i < BNODES; i += 256) cnt[bk * BNODES + i] = hist[i];
}

// ---------------- MFMA GEMM: C[40000][CO] = Abf[40000][128] @ W ----------------
// block = 256 threads = 4 waves; tile = 64 rows x 128 cols.
// Left cols (< Lw) -> bf16 bfL; right cols -> bf16 bfR (if non-null) else fp32 fR.
__global__ __launch_bounds__(256) void gemm_mfma_kernel(const ushort16* __restrict__ Abf,
                                                        const uint4* __restrict__ WfragG,
                                                        int Lw, int Rw,
                                                        ushort16* __restrict__ bfL,
                                                        ushort16* __restrict__ bfR,
                                                        float* __restrict__ fR) {
    __shared__ uint4 Bs[2048];  // 32 KB
    int tid = threadIdx.x;
#pragma unroll
    for (int it = 0; it < 8; ++it) {
        int idx = tid + it * 256;
        Bs[idx] = WfragG[(size_t)blockIdx.y * 2048 + idx];
    }

    int wv = tid >> 6, lane = tid & 63;
    int quad = lane >> 4, c = lane & 15;
    int row0 = blockIdx.x * 64 + wv * 16;

    const uint4* arow = (const uint4*)(Abf + (size_t)(row0 + c) * 128);
    bf16x8 af[4];
#pragma unroll
    for (int s = 0; s < 4; ++s) af[s] = __builtin_bit_cast(bf16x8, arow[s * 4 + quad]);

    __syncthreads();

    f32x4 acc[8];
#pragma unroll
    for (int nt = 0; nt < 8; ++nt) acc[nt] = (f32x4){0.f, 0.f, 0.f, 0.f};

#pragma unroll
    for (int s = 0; s < 4; ++s) {
#pragma unroll
        for (int nt = 0; nt < 8; ++nt) {
            bf16x8 bf = __builtin_bit_cast(bf16x8, Bs[(s * 8 + nt) * 64 + lane]);
            acc[nt] = __builtin_amdgcn_mfma_f32_16x16x32_bf16(af[s], bf, acc[nt], 0, 0, 0);
        }
    }

    int colbase = blockIdx.y * 128;
#pragma unroll
    for (int nt = 0; nt < 8; ++nt) {
        int gcol = colbase + nt * 16 + c;
#pragma unroll
        for (int r = 0; r < 4; ++r) {
            int row = row0 + quad * 4 + r;
            if (gcol < Lw) {
                bfL[(size_t)row * Lw + gcol] = f2bf(acc[nt][r]);
            } else if (bfR) {
                bfR[(size_t)row * Rw + (gcol - Lw)] = f2bf(acc[nt][r]);
            } else {
                fR[(size_t)row * Rw + (gcol - Lw)] = acc[nt][r];
            }
        }
    }
}

// ---------------- layer-1 aggregation: one wave per node, 4-deep uint4 gathers --------
// P4: T1l [N][16] uint4 (128 bf16). S4: T1r bf16 [N][16] uint4. Out hbf4: [N][16] uint4.
// 16-edge groups, 4 gathers in flight; out-of-range slots clamp their shuffle index to
// c-1 (duplicate address -> cache hit) and are predicated out of the accumulate.
__global__ __launch_bounds__(256) void agg1_kernel(const uint4* __restrict__ P4,
                                                   const uint4* __restrict__ S4,
                                                   const int* __restrict__ cnt,
                                                   const unsigned short* __restrict__ csr16,
                                                   const float* __restrict__ b1,
                                                   uint4* __restrict__ hbf4) {
    int wave = threadIdx.x >> 6, lane = threadIdx.x & 63;
    int node = blockIdx.x * 4 + wave;
    if (node >= NNODES) return;
    int c = cnt[node];
    if (c > PAD) c = PAD;
    int sub = lane >> 4;   // edge subset 0..3
    int fl = lane & 15;    // 16B feature chunk
    float s[8];
#pragma unroll
    for (int i = 0; i < 8; ++i) s[i] = 0.f;

    int idx = csr16[(size_t)node * PAD + lane];  // padded bucket: always in-bounds
    int cm1 = c - 1;
    for (int e = 0; e < c; e += 16) {
        int e0 = e + sub, e1 = e + 4 + sub, e2 = e + 8 + sub, e3 = e + 12 + sub;
        int a0 = __shfl(idx, imin(e0, cm1));
        int a1 = __shfl(idx, imin(e1, cm1));
        int a2 = __shfl(idx, imin(e2, cm1));
        int a3 = __shfl(idx, imin(e3, cm1));
        uint4 u0 = P4[(size_t)a0 * 16 + fl];
        uint4 u1 = P4[(size_t)a1 * 16 + fl];
        uint4 u2 = P4[(size_t)a2 * 16 + fl];
        uint4 u3 = P4[(size_t)a3 * 16 + fl];
        if (e0 < c) acc8(s, u0);
        if (e1 < c) acc8(s, u1);
        if (e2 < c) acc8(s, u2);
        if (e3 < c) acc8(s, u3);
    }
    // reduce across the 4 edge-subsets (lanes differing in bits 4,5)
#pragma unroll
    for (int i = 0; i < 8; ++i) s[i] += __shfl_xor(s[i], 16);
#pragma unroll
    for (int i = 0; i < 8; ++i) s[i] += __shfl_xor(s[i], 32);

    if (sub == 0) {
        float ic = 1.0f / (float)(c > 0 ? c : 1);
        uint4 su = S4[(size_t)node * 16 + fl];
        float4 bA = *(const float4*)&b1[fl * 8];
        float4 bB = *(const float4*)&b1[fl * 8 + 4];
        float sv[8];
        sv[0] = bf_lo(su.x); sv[1] = bf_hi(su.x);
        sv[2] = bf_lo(su.y); sv[3] = bf_hi(su.y);
        sv[4] = bf_lo(su.z); sv[5] = bf_hi(su.z);
        sv[6] = bf_lo(su.w); sv[7] = bf_hi(su.w);
        float bb[8] = {bA.x, bA.y, bA.z, bA.w, bB.x, bB.y, bB.z, bB.w};
        float v[8];
#pragma unroll
        for (int i = 0; i < 8; ++i) v[i] = fmaxf(fmaf(s[i], ic, bb[i] + sv[i]), 0.f);
        uint4 o;
        o.x = (uint32)f2bf(v[0]) | ((uint32)f2bf(v[1]) << 16);
        o.y = (uint32)f2bf(v[2]) | ((uint32)f2bf(v[3]) << 16);
        o.z = (uint32)f2bf(v[4]) | ((uint32)f2bf(v[5]) << 16);
        o.w = (uint32)f2bf(v[6]) | ((uint32)f2bf(v[7]) << 16);
        hbf4[(size_t)node * 16 + fl] = o;
    }
}

// ---------------- layer-2 aggregation: one wave per node, 4-deep uint4 gathers --------
// P4: T2l [N][8] uint4 (64 bf16). selfR2: fp32 [N][64]. out: fp32 [N][64].
__global__ __launch_bounds__(256) void agg2_kernel(const uint4* __restrict__ P4,
                                                   const float* __restrict__ selfR2,
                                                   const int* __restrict__ cnt,
                                                   const unsigned short* __restrict__ csr16,
                                                   const float* __restrict__ b2,
                                                   float* __restrict__ out) {
    int wave = threadIdx.x >> 6, lane = threadIdx.x & 63;
    int node = blockIdx.x * 4 + wave;
    if (node >= NNODES) return;
    int c = cnt[node];
    if (c > PAD) c = PAD;
    int sub = lane >> 3;  // edge subset 0..7
    int fl = lane & 7;    // 16B feature chunk
    float s[8];
#pragma unroll
    for (int i = 0; i < 8; ++i) s[i] = 0.f;

    int idx = csr16[(size_t)node * PAD + lane];  // padded bucket: always in-bounds
    int cm1 = c - 1;
    for (int e = 0; e < c; e += 32) {
        int e0 = e + sub, e1 = e + 8 + sub, e2 = e + 16 + sub, e3 = e + 24 + sub;
        int a0 = __shfl(idx, imin(e0, cm1));
        int a1 = __shfl(idx, imin(e1, cm1));
        int a2 = __shfl(idx, imin(e2, cm1));
        int a3 = __shfl(idx, imin(e3, cm1));
        uint4 u0 = P4[(size_t)a0 * 8 + fl];
        uint4 u1 = P4[(size_t)a1 * 8 + fl];
        uint4 u2 = P4[(size_t)a2 * 8 + fl];
        uint4 u3 = P4[(size_t)a3 * 8 + fl];
        if (e0 < c) acc8(s, u0);
        if (e1 < c) acc8(s, u1);
        if (e2 < c) acc8(s, u2);
        if (e3 < c) acc8(s, u3);
    }
#pragma unroll
    for (int i = 0; i < 8; ++i) s[i] += __shfl_xor(s[i], 8);
#pragma unroll
    for (int i = 0; i < 8; ++i) s[i] += __shfl_xor(s[i], 16);
#pragma unroll
    for (int i = 0; i < 8; ++i) s[i] += __shfl_xor(s[i], 32);

    if (sub == 0) {
        float ic = 1.0f / (float)(c > 0 ? c : 1);
        float4 sA = *(const float4*)&selfR2[(size_t)node * 64 + fl * 8];
        float4 sB = *(const float4*)&selfR2[(size_t)node * 64 + fl * 8 + 4];
        float4 bA = *(const float4*)&b2[fl * 8];
        float4 bB = *(const float4*)&b2[fl * 8 + 4];
        float sv[8] = {sA.x, sA.y, sA.z, sA.w, sB.x, sB.y, sB.z, sB.w};
        float bb[8] = {bA.x, bA.y, bA.z, bA.w, bB.x, bB.y, bB.z, bB.w};
        float v[8];
#pragma unroll
        for (int i = 0; i < 8; ++i) v[i] = fmaf(s[i], ic, bb[i] + sv[i]);
        float4 o0 = make_float4(v[0], v[1], v[2], v[3]);
        float4 o1 = make_float4(v[4], v[5], v[6], v[7]);
        *(float4*)&out[(size_t)node * 64 + fl * 8] = o0;
        *(float4*)&out[(size_t)node * 64 + fl * 8 + 4] = o1;
    }
}

extern "C" void kernel_launch(void* const* d_in, const int* in_sizes, int n_in,
                              void* d_out, int out_size, void* d_ws, size_t ws_size,
                              hipStream_t stream) {
    const float* x   = (const float*)d_in[0];
    const void*  ei  = d_in[1];
    const float* W1l = (const float*)d_in[2];
    const float* b1  = (const float*)d_in[3];
    const float* W1r = (const float*)d_in[4];
    const float* W2l = (const float*)d_in[5];
    const float* b2  = (const float*)d_in[6];
    const float* W2r = (const float*)d_in[7];
    float* out = (float*)d_out;

    char* p = (char*)d_ws;
    auto alloc = [&](size_t bytes) {
        char* r = p;
        p += (bytes + 255) & ~(size_t)255;
        return r;
    };
    int*            cnt     = (int*)alloc(NNODES * 4);
    int*            wgcnt   = (int*)alloc((size_t)NBK * NBK * 4);           // 102.4 KB
    int*            bstream = (int*)alloc((size_t)NBK * NBK * SCAP * 4);    // 8.19 MB
    unsigned short* csr16   = (unsigned short*)alloc((size_t)NNODES * PAD * 2);  // 5.12 MB
    ushort16*       Wfrag1  = (ushort16*)alloc(32768 * 2);
    ushort16*       Wfrag2  = (ushort16*)alloc(16384 * 2);
    uint32*         xbf     = (uint32*)alloc((size_t)NNODES * 64 * 4);      // x bf16
    ushort16*       T1l     = (ushort16*)alloc((size_t)NNODES * 128 * 2);   // bf16 payload
    ushort16*       T1r     = (ushort16*)alloc((size_t)NNODES * 128 * 2);   // bf16 self
    uint32*         hbf     = (uint32*)alloc((size_t)NNODES * 64 * 4);      // h bf16
    ushort16*       T2l     = (ushort16*)alloc((size_t)NNODES * 64 * 2);
    float*          T2r     = (float*)alloc((size_t)NNODES * 64 * 4);

    // fused conv + pack + single-pass buildA (5000 + 192 + 160 blocks)
    prep_build_kernel<<<5352, 256, 0, stream>>>(x, xbf, W1l, W1r, W2l, W2r, Wfrag1, Wfrag2,
                                                ei, (const int*)ei, bstream, wgcnt);
    // buildB: slice sweep -> LDS image -> dense ushort CSR
    buildB_kernel<<<NBK, 256, 0, stream>>>(bstream, wgcnt, cnt, csr16);

    // layer 1: T1 = xbf @ [W1l | W1r]; left 128 -> bf16 payload, right 128 -> bf16 self
    gemm_mfma_kernel<<<dim3(NNODES / 64, 2), 256, 0, stream>>>(
        (const ushort16*)xbf, (const uint4*)Wfrag1, 128, 128, T1l, T1r, (float*)nullptr);
    agg1_kernel<<<(NNODES + 3) / 4, 256, 0, stream>>>((const uint4*)T1l, (const uint4*)T1r,
                                                      cnt, csr16, b1, (uint4*)hbf);

    // layer 2: T2 = hbf @ [W2l | W2r]; left 64 -> bf16 payload, right 64 -> fp32 self
    gemm_mfma_kernel<<<dim3(NNODES / 64, 1), 256, 0, stream>>>(
        (const ushort16*)hbf, (const uint4*)Wfrag2, 64, 64, T2l, (ushort16*)nullptr, T2r);
    agg2_kernel<<<(NNODES + 3) / 4, 256, 0, stream>>>((const uint4*)T2l, T2r, cnt, csr16, b2,
                                                      out);
}

// Round 10
// 169.735 us; speedup vs baseline: 1.1151x; 1.1151x over previous
//
#include <hip/hip_runtime.h>

#define NNODES 40000
#define NEDGES 640000
#define PAD 64
#define NBK 160           // dst-range buckets
#define BNODES 250        // nodes per bucket (160*250 = 40000)
#define BCAP 8192         // bucket stream capacity (mean 4000, Poisson)
#define ACHUNK 4000       // edges per buildA WG (160*4000 = 640000)
// IN_F = 128, HID = 128, OUT_F = 64

typedef unsigned int uint32;
typedef unsigned short ushort16;
typedef short bf16x8 __attribute__((ext_vector_type(8)));
typedef float f32x4 __attribute__((ext_vector_type(4)));

// ---------------- bf16 helpers ----------------
static __device__ __forceinline__ ushort16 f2bf(float f) {
    uint32 u = __builtin_bit_cast(uint32, f);
    uint32 r = u + 0x7fffu + ((u >> 16) & 1u);  // RNE
    return (ushort16)(r >> 16);
}
static __device__ __forceinline__ float bf_lo(uint32 u) {
    uint32 t = u << 16;
    return __builtin_bit_cast(float, t);
}
static __device__ __forceinline__ float bf_hi(uint32 u) {
    uint32 t = u & 0xffff0000u;
    return __builtin_bit_cast(float, t);
}

static __device__ __forceinline__ void acc8(float* s, uint4 u) {
    s[0] += bf_lo(u.x); s[1] += bf_hi(u.x);
    s[2] += bf_lo(u.y); s[3] += bf_hi(u.y);
    s[4] += bf_lo(u.z); s[5] += bf_hi(u.z);
    s[6] += bf_lo(u.w); s[7] += bf_hi(u.w);
}

static __device__ __forceinline__ int edge_val(const void* ep, long long idx, int is64) {
    if (is64) return (int)((const long long*)ep)[idx];
    return ((const int*)ep)[idx];
}

static __device__ __forceinline__ int imin(int a, int b) { return a < b ? a : b; }

// ---------------- fused prep: x -> bf16 AND weight packing + dtype flag + gcur zero ----
// blocks [0, 5000): conv part (n4 = 1,280,000 float4 = exactly 5000*256)
// blocks [5000, 5192): pack part (49152 threads). Dtype probe is a 64-lane ballot
// (one coalesced load) instead of a 64-load serial chain on one thread.
__global__ void prep_kernel(const float* __restrict__ x, uint32* __restrict__ xbf2,
                            int* __restrict__ gcur,
                            const float* __restrict__ W1l, const float* __restrict__ W1r,
                            const float* __restrict__ W2l, const float* __restrict__ W2r,
                            ushort16* __restrict__ Wfrag1, ushort16* __restrict__ Wfrag2,
                            const int* __restrict__ e32, int* __restrict__ flag) {
    int b = blockIdx.x;
    if (b < 5000) {
        int i = b * 256 + threadIdx.x;
        float4 v = ((const float4*)x)[i];
        uint2 o;
        o.x = (uint32)f2bf(v.x) | ((uint32)f2bf(v.y) << 16);
        o.y = (uint32)f2bf(v.z) | ((uint32)f2bf(v.w) << 16);
        ((uint2*)xbf2)[i] = o;
        return;
    }
    int i = (b - 5000) * 256 + threadIdx.x;  // 49152 total
    if (i < NBK) gcur[i] = 0;
    if (b == 5000 && threadIdx.x < 64) {  // wave 0: parallel int64-hi-word probe
        int v = e32[2 * threadIdx.x + 1];
        unsigned long long m = __ballot(v != 0);
        if (threadIdx.x == 0) *flag = (m == 0ull) ? 1 : 0;
    }
    if (i < 32768) {
        int j = i & 7, lane = (i >> 3) & 63, nt = (i >> 9) & 7, s = (i >> 12) & 3, by = i >> 14;
        int k = s * 32 + (lane >> 4) * 8 + j;
        int col = nt * 16 + (lane & 15);
        float v = (by == 0) ? W1l[k * 128 + col] : W1r[k * 128 + col];
        Wfrag1[i] = f2bf(v);
    } else {
        int q = i - 32768;  // 16384
        int j = q & 7, lane = (q >> 3) & 63, nt = (q >> 9) & 7, s = (q >> 12) & 3;
        int k = s * 32 + (lane >> 4) * 8 + j;
        int col = nt * 16 + (lane & 15);
        float v = (col < 64) ? W2l[k * 64 + col] : W2r[k * 64 + (col - 64)];
        Wfrag2[q] = f2bf(v);
    }
}

// ---------------- buildA: radix partition edges into 160 dst-range bucket streams ----
// Temporal write locality inside one WG: per-WG reserved contiguous ranges, ~25-entry
// runs written once. Entry packs (src<<8)|dloc, dloc = d - bucket*250 < 250.
__global__ __launch_bounds__(256) void buildA_kernel(const void* __restrict__ edges,
                                                     const int* __restrict__ flag,
                                                     int* __restrict__ gcur,
                                                     int* __restrict__ bstream) {
    __shared__ int hist[NBK];
    __shared__ int cur[NBK];
    int tid = threadIdx.x;
    int base = blockIdx.x * ACHUNK;
    for (int i = tid; i < NBK; i += 256) hist[i] = 0;
    __syncthreads();
    int is64 = *flag;
#pragma unroll
    for (int k = 0; k < (ACHUNK + 255) / 256; ++k) {
        int off = k * 256 + tid;
        if (off < ACHUNK) {
            int d = edge_val(edges, (long long)NEDGES + base + off, is64);
            atomicAdd(&hist[d / BNODES], 1);
        }
    }
    __syncthreads();
    if (tid < NBK) cur[tid] = atomicAdd(&gcur[tid], hist[tid]);
    __syncthreads();
#pragma unroll
    for (int k = 0; k < (ACHUNK + 255) / 256; ++k) {
        int off = k * 256 + tid;
        if (off < ACHUNK) {
            int e = base + off;
            int d = edge_val(edges, (long long)NEDGES + e, is64);
            int s = edge_val(edges, e, is64);
            int bk = d / BNODES;
            int dloc = d - bk * BNODES;
            int r = atomicAdd(&cur[bk], 1);
            if (r < BCAP) bstream[bk * BCAP + r] = (s << 8) | dloc;
        }
    }
}

// ---------------- buildB: per-bucket LDS regroup -> dense USHORT padded-CSR -----------
// src ids fit in 16 bits (N=40000). 32 KB LDS image, dense uint4 writeback (5.12 MB).
__global__ __launch_bounds__(256) void buildB_kernel(const int* __restrict__ bstream,
                                                     const int* __restrict__ gcur,
                                                     int* __restrict__ cnt,
                                                     unsigned short* __restrict__ csr16) {
    __shared__ uint4 img4[BNODES * 8];  // 32000 B (250 x 64 ushort)
    __shared__ int hist[BNODES];
    unsigned short* img = (unsigned short*)img4;
    int tid = threadIdx.x;
    int bk = blockIdx.x;
    for (int i = tid; i < BNODES; i += 256) hist[i] = 0;
    __syncthreads();
    int n = gcur[bk];
    if (n > BCAP) n = BCAP;
    for (int i = tid; i < n; i += 256) {
        int u = bstream[bk * BCAP + i];
        int dloc = u & 255;
        int r = atomicAdd(&hist[dloc], 1);
        if (r < PAD) img[dloc * PAD + r] = (unsigned short)(u >> 8);
    }
    __syncthreads();
    uint4* dst = (uint4*)(csr16 + (size_t)bk * BNODES * PAD);
#pragma unroll
    for (int i = tid; i < BNODES * 8; i += 256) dst[i] = img4[i];
    for (int i = tid; i < BNODES; i += 256) cnt[bk * BNODES + i] = hist[i];
}

// ---------------- MFMA GEMM: C[40000][CO] = Abf[40000][128] @ W ----------------
// block = 256 threads = 4 waves; tile = 64 rows x 128 cols.
// Left cols (< Lw) -> bf16 bfL; right cols -> bf16 bfR (if non-null) else fp32 fR.
__global__ __launch_bounds__(256) void gemm_mfma_kernel(const ushort16* __restrict__ Abf,
                                                        const uint4* __restrict__ WfragG,
                                                        int Lw, int Rw,
                                                        ushort16* __restrict__ bfL,
                                                        ushort16* __restrict__ bfR,
                                                        float* __restrict__ fR) {
    __shared__ uint4 Bs[2048];  // 32 KB
    int tid = threadIdx.x;
#pragma unroll
    for (int it = 0; it < 8; ++it) {
        int idx = tid + it * 256;
        Bs[idx] = WfragG[(size_t)blockIdx.y * 2048 + idx];
    }

    int wv = tid >> 6, lane = tid & 63;
    int quad = lane >> 4, c = lane & 15;
    int row0 = blockIdx.x * 64 + wv * 16;

    const uint4* arow = (const uint4*)(Abf + (size_t)(row0 + c) * 128);
    bf16x8 af[4];
#pragma unroll
    for (int s = 0; s < 4; ++s) af[s] = __builtin_bit_cast(bf16x8, arow[s * 4 + quad]);

    __syncthreads();

    f32x4 acc[8];
#pragma unroll
    for (int nt = 0; nt < 8; ++nt) acc[nt] = (f32x4){0.f, 0.f, 0.f, 0.f};

#pragma unroll
    for (int s = 0; s < 4; ++s) {
#pragma unroll
        for (int nt = 0; nt < 8; ++nt) {
            bf16x8 bf = __builtin_bit_cast(bf16x8, Bs[(s * 8 + nt) * 64 + lane]);
            acc[nt] = __builtin_amdgcn_mfma_f32_16x16x32_bf16(af[s], bf, acc[nt], 0, 0, 0);
        }
    }

    int colbase = blockIdx.y * 128;
#pragma unroll
    for (int nt = 0; nt < 8; ++nt) {
        int gcol = colbase + nt * 16 + c;
#pragma unroll
        for (int r = 0; r < 4; ++r) {
            int row = row0 + quad * 4 + r;
            if (gcol < Lw) {
                bfL[(size_t)row * Lw + gcol] = f2bf(acc[nt][r]);
            } else if (bfR) {
                bfR[(size_t)row * Rw + (gcol - Lw)] = f2bf(acc[nt][r]);
            } else {
                fR[(size_t)row * Rw + (gcol - Lw)] = acc[nt][r];
            }
        }
    }
}

// ---------------- layer-1 aggregation: one wave per node, 8-deep uint4 gathers --------
// P4: T1l [N][16] uint4 (128 bf16). S4: T1r bf16 [N][16] uint4. Out hbf4: [N][16] uint4.
// 32-edge groups, 8 gathers in flight; out-of-range slots clamp their shuffle index to
// c-1 (duplicate address -> cache hit) and are predicated out of the accumulate.
__global__ __launch_bounds__(256) void agg1_kernel(const uint4* __restrict__ P4,
                                                   const uint4* __restrict__ S4,
                                                   const int* __restrict__ cnt,
                                                   const unsigned short* __restrict__ csr16,
                                                   const float* __restrict__ b1,
                                                   uint4* __restrict__ hbf4) {
    int wave = threadIdx.x >> 6, lane = threadIdx.x & 63;
    int node = blockIdx.x * 4 + wave;
    if (node >= NNODES) return;
    int c = cnt[node];
    if (c > PAD) c = PAD;
    int sub = lane >> 4;   // edge subset 0..3
    int fl = lane & 15;    // 16B feature chunk
    float s[8];
#pragma unroll
    for (int i = 0; i < 8; ++i) s[i] = 0.f;

    int idx = csr16[(size_t)node * PAD + lane];  // padded bucket: always in-bounds
    int cm1 = c - 1;
    for (int e = 0; e < c; e += 32) {
        int e0 = e + sub, e1 = e + 4 + sub, e2 = e + 8 + sub, e3 = e + 12 + sub;
        int e4 = e + 16 + sub, e5 = e + 20 + sub, e6 = e + 24 + sub, e7 = e + 28 + sub;
        int a0 = __shfl(idx, imin(e0, cm1));
        int a1 = __shfl(idx, imin(e1, cm1));
        int a2 = __shfl(idx, imin(e2, cm1));
        int a3 = __shfl(idx, imin(e3, cm1));
        int a4 = __shfl(idx, imin(e4, cm1));
        int a5 = __shfl(idx, imin(e5, cm1));
        int a6 = __shfl(idx, imin(e6, cm1));
        int a7 = __shfl(idx, imin(e7, cm1));
        uint4 u0 = P4[(size_t)a0 * 16 + fl];
        uint4 u1 = P4[(size_t)a1 * 16 + fl];
        uint4 u2 = P4[(size_t)a2 * 16 + fl];
        uint4 u3 = P4[(size_t)a3 * 16 + fl];
        uint4 u4 = P4[(size_t)a4 * 16 + fl];
        uint4 u5 = P4[(size_t)a5 * 16 + fl];
        uint4 u6 = P4[(size_t)a6 * 16 + fl];
        uint4 u7 = P4[(size_t)a7 * 16 + fl];
        if (e0 < c) acc8(s, u0);
        if (e1 < c) acc8(s, u1);
        if (e2 < c) acc8(s, u2);
        if (e3 < c) acc8(s, u3);
        if (e4 < c) acc8(s, u4);
        if (e5 < c) acc8(s, u5);
        if (e6 < c) acc8(s, u6);
        if (e7 < c) acc8(s, u7);
    }
    // reduce across the 4 edge-subsets (lanes differing in bits 4,5)
#pragma unroll
    for (int i = 0; i < 8; ++i) s[i] += __shfl_xor(s[i], 16);
#pragma unroll
    for (int i = 0; i < 8; ++i) s[i] += __shfl_xor(s[i], 32);

    if (sub == 0) {
        float ic = 1.0f / (float)(c > 0 ? c : 1);
        uint4 su = S4[(size_t)node * 16 + fl];
        float4 bA = *(const float4*)&b1[fl * 8];
        float4 bB = *(const float4*)&b1[fl * 8 + 4];
        float sv[8];
        sv[0] = bf_lo(su.x); sv[1] = bf_hi(su.x);
        sv[2] = bf_lo(su.y); sv[3] = bf_hi(su.y);
        sv[4] = bf_lo(su.z); sv[5] = bf_hi(su.z);
        sv[6] = bf_lo(su.w); sv[7] = bf_hi(su.w);
        float bb[8] = {bA.x, bA.y, bA.z, bA.w, bB.x, bB.y, bB.z, bB.w};
        float v[8];
#pragma unroll
        for (int i = 0; i < 8; ++i) v[i] = fmaxf(fmaf(s[i], ic, bb[i] + sv[i]), 0.f);
        uint4 o;
        o.x = (uint32)f2bf(v[0]) | ((uint32)f2bf(v[1]) << 16);
        o.y = (uint32)f2bf(v[2]) | ((uint32)f2bf(v[3]) << 16);
        o.z = (uint32)f2bf(v[4]) | ((uint32)f2bf(v[5]) << 16);
        o.w = (uint32)f2bf(v[6]) | ((uint32)f2bf(v[7]) << 16);
        hbf4[(size_t)node * 16 + fl] = o;
    }
}

// ---------------- layer-2 aggregation: one wave per node, 4-deep uint4 gathers --------
// P4: T2l [N][8] uint4 (64 bf16). selfR2: fp32 [N][64]. out: fp32 [N][64].
__global__ __launch_bounds__(256) void agg2_kernel(const uint4* __restrict__ P4,
                                                   const float* __restrict__ selfR2,
                                                   const int* __restrict__ cnt,
                                                   const unsigned short* __restrict__ csr16,
                                                   const float* __restrict__ b2,
                                                   float* __restrict__ out) {
    int wave = threadIdx.x >> 6, lane = threadIdx.x & 63;
    int node = blockIdx.x * 4 + wave;
    if (node >= NNODES) return;
    int c = cnt[node];
    if (c > PAD) c = PAD;
    int sub = lane >> 3;  // edge subset 0..7
    int fl = lane & 7;    // 16B feature chunk
    float s[8];
#pragma unroll
    for (int i = 0; i < 8; ++i) s[i] = 0.f;

    int idx = csr16[(size_t)node * PAD + lane];  // padded bucket: always in-bounds
    int cm1 = c - 1;
    for (int e = 0; e < c; e += 32) {
        int e0 = e + sub, e1 = e + 8 + sub, e2 = e + 16 + sub, e3 = e + 24 + sub;
        int a0 = __shfl(idx, imin(e0, cm1));
        int a1 = __shfl(idx, imin(e1, cm1));
        int a2 = __shfl(idx, imin(e2, cm1));
        int a3 = __shfl(idx, imin(e3, cm1));
        uint4 u0 = P4[(size_t)a0 * 8 + fl];
        uint4 u1 = P4[(size_t)a1 * 8 + fl];
        uint4 u2 = P4[(size_t)a2 * 8 + fl];
        uint4 u3 = P4[(size_t)a3 * 8 + fl];
        if (e0 < c) acc8(s, u0);
        if (e1 < c) acc8(s, u1);
        if (e2 < c) acc8(s, u2);
        if (e3 < c) acc8(s, u3);
    }
#pragma unroll
    for (int i = 0; i < 8; ++i) s[i] += __shfl_xor(s[i], 8);
#pragma unroll
    for (int i = 0; i < 8; ++i) s[i] += __shfl_xor(s[i], 16);
#pragma unroll
    for (int i = 0; i < 8; ++i) s[i] += __shfl_xor(s[i], 32);

    if (sub == 0) {
        float ic = 1.0f / (float)(c > 0 ? c : 1);
        float4 sA = *(const float4*)&selfR2[(size_t)node * 64 + fl * 8];
        float4 sB = *(const float4*)&selfR2[(size_t)node * 64 + fl * 8 + 4];
        float4 bA = *(const float4*)&b2[fl * 8];
        float4 bB = *(const float4*)&b2[fl * 8 + 4];
        float sv[8] = {sA.x, sA.y, sA.z, sA.w, sB.x, sB.y, sB.z, sB.w};
        float bb[8] = {bA.x, bA.y, bA.z, bA.w, bB.x, bB.y, bB.z, bB.w};
        float v[8];
#pragma unroll
        for (int i = 0; i < 8; ++i) v[i] = fmaf(s[i], ic, bb[i] + sv[i]);
        float4 o0 = make_float4(v[0], v[1], v[2], v[3]);
        float4 o1 = make_float4(v[4], v[5], v[6], v[7]);
        *(float4*)&out[(size_t)node * 64 + fl * 8] = o0;
        *(float4*)&out[(size_t)node * 64 + fl * 8 + 4] = o1;
    }
}

extern "C" void kernel_launch(void* const* d_in, const int* in_sizes, int n_in,
                              void* d_out, int out_size, void* d_ws, size_t ws_size,
                              hipStream_t stream) {
    const float* x   = (const float*)d_in[0];
    const void*  ei  = d_in[1];
    const float* W1l = (const float*)d_in[2];
    const float* b1  = (const float*)d_in[3];
    const float* W1r = (const float*)d_in[4];
    const float* W2l = (const float*)d_in[5];
    const float* b2  = (const float*)d_in[6];
    const float* W2r = (const float*)d_in[7];
    float* out = (float*)d_out;

    char* p = (char*)d_ws;
    auto alloc = [&](size_t bytes) {
        char* r = p;
        p += (bytes + 255) & ~(size_t)255;
        return r;
    };
    int*            flag    = (int*)alloc(4);
    int*            cnt     = (int*)alloc(NNODES * 4);
    int*            gcur    = (int*)alloc(NBK * 4);
    int*            bstream = (int*)alloc((size_t)NBK * BCAP * 4);        // 5.24 MB
    unsigned short* csr16   = (unsigned short*)alloc((size_t)NNODES * PAD * 2);  // 5.12 MB
    ushort16*       Wfrag1  = (ushort16*)alloc(32768 * 2);
    ushort16*       Wfrag2  = (ushort16*)alloc(16384 * 2);
    uint32*         xbf     = (uint32*)alloc((size_t)NNODES * 64 * 4);    // x bf16
    ushort16*       T1l     = (ushort16*)alloc((size_t)NNODES * 128 * 2); // bf16 payload
    ushort16*       T1r     = (ushort16*)alloc((size_t)NNODES * 128 * 2); // bf16 self
    uint32*         hbf     = (uint32*)alloc((size_t)NNODES * 64 * 4);    // h bf16
    ushort16*       T2l     = (ushort16*)alloc((size_t)NNODES * 64 * 2);
    float*          T2r     = (float*)alloc((size_t)NNODES * 64 * 4);

    // fused conv+pack+flag+gcur-zero
    prep_kernel<<<5192, 256, 0, stream>>>(x, xbf, gcur, W1l, W1r, W2l, W2r, Wfrag1, Wfrag2,
                                          (const int*)ei, flag);
    // radix CSR build: partition into bucket streams, then LDS regroup -> ushort CSR
    buildA_kernel<<<NBK, 256, 0, stream>>>(ei, flag, gcur, bstream);
    buildB_kernel<<<NBK, 256, 0, stream>>>(bstream, gcur, cnt, csr16);

    // layer 1: T1 = xbf @ [W1l | W1r]; left 128 -> bf16 payload, right 128 -> bf16 self
    gemm_mfma_kernel<<<dim3(NNODES / 64, 2), 256, 0, stream>>>(
        (const ushort16*)xbf, (const uint4*)Wfrag1, 128, 128, T1l, T1r, (float*)nullptr);
    agg1_kernel<<<(NNODES + 3) / 4, 256, 0, stream>>>((const uint4*)T1l, (const uint4*)T1r,
                                                      cnt, csr16, b1, (uint4*)hbf);

    // layer 2: T2 = hbf @ [W2l | W2r]; left 64 -> bf16 payload, right 64 -> fp32 self
    gemm_mfma_kernel<<<dim3(NNODES / 64, 1), 256, 0, stream>>>(
        (const ushort16*)hbf, (const uint4*)Wfrag2, 64, 64, T2l, (ushort16*)nullptr, T2r);
    agg2_kernel<<<(NNODES + 3) / 4, 256, 0, stream>>>((const uint4*)T2l, T2r, cnt, csr16, b2,
                                                      out);
}

// Round 11
// 166.485 us; speedup vs baseline: 1.1368x; 1.0195x over previous
//
#include <hip/hip_runtime.h>

#define NNODES 40000
#define NEDGES 640000
#define PAD 64
#define NBK 160           // dst-range buckets
#define BNODES 250        // nodes per bucket (160*250 = 40000)
#define BCAP 8192         // bucket stream capacity (mean 4000, Poisson)
#define ACHUNK 4000       // edges per buildA WG (160*4000 = 640000)
// IN_F = 128, HID = 128, OUT_F = 64

typedef unsigned int uint32;
typedef unsigned short ushort16;
typedef short bf16x8 __attribute__((ext_vector_type(8)));
typedef float f32x4 __attribute__((ext_vector_type(4)));

// ---------------- bf16 helpers ----------------
static __device__ __forceinline__ ushort16 f2bf(float f) {
    uint32 u = __builtin_bit_cast(uint32, f);
    uint32 r = u + 0x7fffu + ((u >> 16) & 1u);  // RNE
    return (ushort16)(r >> 16);
}
static __device__ __forceinline__ float bf_lo(uint32 u) {
    uint32 t = u << 16;
    return __builtin_bit_cast(float, t);
}
static __device__ __forceinline__ float bf_hi(uint32 u) {
    uint32 t = u & 0xffff0000u;
    return __builtin_bit_cast(float, t);
}

static __device__ __forceinline__ void acc8(float* s, uint4 u) {
    s[0] += bf_lo(u.x); s[1] += bf_hi(u.x);
    s[2] += bf_lo(u.y); s[3] += bf_hi(u.y);
    s[4] += bf_lo(u.z); s[5] += bf_hi(u.z);
    s[6] += bf_lo(u.w); s[7] += bf_hi(u.w);
}

static __device__ __forceinline__ int edge_val(const void* ep, long long idx, int is64) {
    if (is64) return (int)((const long long*)ep)[idx];
    return ((const int*)ep)[idx];
}

static __device__ __forceinline__ int imin(int a, int b) { return a < b ? a : b; }

// ---------------- prep: weight packing + dtype flag + gcur zero (192 blocks) ----------
// x is no longer materialized as bf16 — gemm1 reads fp32 directly and converts
// in-register, removing a 20.5 MB read + 10.25 MB write pass.
__global__ void prep_kernel(int* __restrict__ gcur,
                            const float* __restrict__ W1l, const float* __restrict__ W1r,
                            const float* __restrict__ W2l, const float* __restrict__ W2r,
                            ushort16* __restrict__ Wfrag1, ushort16* __restrict__ Wfrag2,
                            const int* __restrict__ e32, int* __restrict__ flag) {
    int i = blockIdx.x * 256 + threadIdx.x;  // 49152 total
    if (i < NBK) gcur[i] = 0;
    if (blockIdx.x == 0 && threadIdx.x < 64) {  // wave 0: parallel int64-hi-word probe
        int v = e32[2 * threadIdx.x + 1];
        unsigned long long m = __ballot(v != 0);
        if (threadIdx.x == 0) *flag = (m == 0ull) ? 1 : 0;
    }
    if (i < 32768) {
        int j = i & 7, lane = (i >> 3) & 63, nt = (i >> 9) & 7, s = (i >> 12) & 3, by = i >> 14;
        int k = s * 32 + (lane >> 4) * 8 + j;
        int col = nt * 16 + (lane & 15);
        float v = (by == 0) ? W1l[k * 128 + col] : W1r[k * 128 + col];
        Wfrag1[i] = f2bf(v);
    } else {
        int q = i - 32768;  // 16384
        int j = q & 7, lane = (q >> 3) & 63, nt = (q >> 9) & 7, s = (q >> 12) & 3;
        int k = s * 32 + (lane >> 4) * 8 + j;
        int col = nt * 16 + (lane & 15);
        float v = (col < 64) ? W2l[k * 64 + col] : W2r[k * 64 + (col - 64)];
        Wfrag2[q] = f2bf(v);
    }
}

// ---------------- buildA: radix partition edges into 160 dst-range bucket streams ----
// Temporal write locality inside one WG: per-WG reserved contiguous ranges, ~25-entry
// runs written once. Entry packs (src<<8)|dloc, dloc = d - bucket*250 < 250.
__global__ __launch_bounds__(256) void buildA_kernel(const void* __restrict__ edges,
                                                     const int* __restrict__ flag,
                                                     int* __restrict__ gcur,
                                                     int* __restrict__ bstream) {
    __shared__ int hist[NBK];
    __shared__ int cur[NBK];
    int tid = threadIdx.x;
    int base = blockIdx.x * ACHUNK;
    for (int i = tid; i < NBK; i += 256) hist[i] = 0;
    __syncthreads();
    int is64 = *flag;
#pragma unroll
    for (int k = 0; k < (ACHUNK + 255) / 256; ++k) {
        int off = k * 256 + tid;
        if (off < ACHUNK) {
            int d = edge_val(edges, (long long)NEDGES + base + off, is64);
            atomicAdd(&hist[d / BNODES], 1);
        }
    }
    __syncthreads();
    if (tid < NBK) cur[tid] = atomicAdd(&gcur[tid], hist[tid]);
    __syncthreads();
#pragma unroll
    for (int k = 0; k < (ACHUNK + 255) / 256; ++k) {
        int off = k * 256 + tid;
        if (off < ACHUNK) {
            int e = base + off;
            int d = edge_val(edges, (long long)NEDGES + e, is64);
            int s = edge_val(edges, e, is64);
            int bk = d / BNODES;
            int dloc = d - bk * BNODES;
            int r = atomicAdd(&cur[bk], 1);
            if (r < BCAP) bstream[bk * BCAP + r] = (s << 8) | dloc;
        }
    }
}

// ---------------- buildB: per-bucket LDS regroup -> dense USHORT padded-CSR -----------
// src ids fit in 16 bits (N=40000). 32 KB LDS image, dense uint4 writeback (5.12 MB).
__global__ __launch_bounds__(256) void buildB_kernel(const int* __restrict__ bstream,
                                                     const int* __restrict__ gcur,
                                                     int* __restrict__ cnt,
                                                     unsigned short* __restrict__ csr16) {
    __shared__ uint4 img4[BNODES * 8];  // 32000 B (250 x 64 ushort)
    __shared__ int hist[BNODES];
    unsigned short* img = (unsigned short*)img4;
    int tid = threadIdx.x;
    int bk = blockIdx.x;
    for (int i = tid; i < BNODES; i += 256) hist[i] = 0;
    __syncthreads();
    int n = gcur[bk];
    if (n > BCAP) n = BCAP;
    for (int i = tid; i < n; i += 256) {
        int u = bstream[bk * BCAP + i];
        int dloc = u & 255;
        int r = atomicAdd(&hist[dloc], 1);
        if (r < PAD) img[dloc * PAD + r] = (unsigned short)(u >> 8);
    }
    __syncthreads();
    uint4* dst = (uint4*)(csr16 + (size_t)bk * BNODES * PAD);
#pragma unroll
    for (int i = tid; i < BNODES * 8; i += 256) dst[i] = img4[i];
    for (int i = tid; i < BNODES; i += 256) cnt[bk * BNODES + i] = hist[i];
}

// ---------------- layer-1 MFMA GEMM, fp32 A direct: T1 = bf16(x) @ [W1l | W1r] --------
// Reads x fp32 (20.5 MB) and converts to bf16 fragments in-register (8 f2bf per frag,
// hidden under MFMA). Left 128 cols -> bf16 T1l, right 128 -> bf16 T1r.
__global__ __launch_bounds__(256) void gemm1_kernel(const float* __restrict__ X,
                                                    const uint4* __restrict__ WfragG,
                                                    ushort16* __restrict__ bfL,
                                                    ushort16* __restrict__ bfR) {
    __shared__ uint4 Bs[2048];  // 32 KB
    int tid = threadIdx.x;
#pragma unroll
    for (int it = 0; it < 8; ++it) {
        int idx = tid + it * 256;
        Bs[idx] = WfragG[(size_t)blockIdx.y * 2048 + idx];
    }

    int wv = tid >> 6, lane = tid & 63;
    int quad = lane >> 4, c = lane & 15;
    int row0 = blockIdx.x * 64 + wv * 16;

    const float* xrow = X + (size_t)(row0 + c) * 128;
    bf16x8 af[4];
#pragma unroll
    for (int s = 0; s < 4; ++s) {
        const float4* fp = (const float4*)(xrow + s * 32 + quad * 8);
        float4 va = fp[0], vb = fp[1];
        af[s] = (bf16x8){(short)f2bf(va.x), (short)f2bf(va.y), (short)f2bf(va.z),
                         (short)f2bf(va.w), (short)f2bf(vb.x), (short)f2bf(vb.y),
                         (short)f2bf(vb.z), (short)f2bf(vb.w)};
    }

    __syncthreads();

    f32x4 acc[8];
#pragma unroll
    for (int nt = 0; nt < 8; ++nt) acc[nt] = (f32x4){0.f, 0.f, 0.f, 0.f};

#pragma unroll
    for (int s = 0; s < 4; ++s) {
#pragma unroll
        for (int nt = 0; nt < 8; ++nt) {
            bf16x8 bf = __builtin_bit_cast(bf16x8, Bs[(s * 8 + nt) * 64 + lane]);
            acc[nt] = __builtin_amdgcn_mfma_f32_16x16x32_bf16(af[s], bf, acc[nt], 0, 0, 0);
        }
    }

    int colbase = blockIdx.y * 128;
#pragma unroll
    for (int nt = 0; nt < 8; ++nt) {
        int gcol = colbase + nt * 16 + c;
#pragma unroll
        for (int r = 0; r < 4; ++r) {
            int row = row0 + quad * 4 + r;
            if (gcol < 128) {
                bfL[(size_t)row * 128 + gcol] = f2bf(acc[nt][r]);
            } else {
                bfR[(size_t)row * 128 + (gcol - 128)] = f2bf(acc[nt][r]);
            }
        }
    }
}

// ---------------- layer-2 MFMA GEMM (bf16 A): T2 = hbf @ [W2l | W2r] ------------------
// Left cols (< Lw) -> bf16 bfL; right cols -> fp32 fR.
__global__ __launch_bounds__(256) void gemm_mfma_kernel(const ushort16* __restrict__ Abf,
                                                        const uint4* __restrict__ WfragG,
                                                        int Lw, int Rw,
                                                        ushort16* __restrict__ bfL,
                                                        float* __restrict__ fR) {
    __shared__ uint4 Bs[2048];  // 32 KB
    int tid = threadIdx.x;
#pragma unroll
    for (int it = 0; it < 8; ++it) {
        int idx = tid + it * 256;
        Bs[idx] = WfragG[(size_t)blockIdx.y * 2048 + idx];
    }

    int wv = tid >> 6, lane = tid & 63;
    int quad = lane >> 4, c = lane & 15;
    int row0 = blockIdx.x * 64 + wv * 16;

    const uint4* arow = (const uint4*)(Abf + (size_t)(row0 + c) * 128);
    bf16x8 af[4];
#pragma unroll
    for (int s = 0; s < 4; ++s) af[s] = __builtin_bit_cast(bf16x8, arow[s * 4 + quad]);

    __syncthreads();

    f32x4 acc[8];
#pragma unroll
    for (int nt = 0; nt < 8; ++nt) acc[nt] = (f32x4){0.f, 0.f, 0.f, 0.f};

#pragma unroll
    for (int s = 0; s < 4; ++s) {
#pragma unroll
        for (int nt = 0; nt < 8; ++nt) {
            bf16x8 bf = __builtin_bit_cast(bf16x8, Bs[(s * 8 + nt) * 64 + lane]);
            acc[nt] = __builtin_amdgcn_mfma_f32_16x16x32_bf16(af[s], bf, acc[nt], 0, 0, 0);
        }
    }

    int colbase = blockIdx.y * 128;
#pragma unroll
    for (int nt = 0; nt < 8; ++nt) {
        int gcol = colbase + nt * 16 + c;
#pragma unroll
        for (int r = 0; r < 4; ++r) {
            int row = row0 + quad * 4 + r;
            if (gcol < Lw) {
                bfL[(size_t)row * Lw + gcol] = f2bf(acc[nt][r]);
            } else {
                fR[(size_t)row * Rw + (gcol - Lw)] = acc[nt][r];
            }
        }
    }
}

// ---------------- layer-1 aggregation: one wave per node, 8-deep uint4 gathers --------
// P4: T1l [N][16] uint4 (128 bf16). S4: T1r bf16 [N][16] uint4. Out hbf4: [N][16] uint4.
// 32-edge groups, 8 gathers in flight; out-of-range slots clamp their shuffle index to
// c-1 (duplicate address -> cache hit) and are predicated out of the accumulate.
__global__ __launch_bounds__(256) void agg1_kernel(const uint4* __restrict__ P4,
                                                   const uint4* __restrict__ S4,
                                                   const int* __restrict__ cnt,
                                                   const unsigned short* __restrict__ csr16,
                                                   const float* __restrict__ b1,
                                                   uint4* __restrict__ hbf4) {
    int wave = threadIdx.x >> 6, lane = threadIdx.x & 63;
    int node = blockIdx.x * 4 + wave;
    if (node >= NNODES) return;
    int c = cnt[node];
    if (c > PAD) c = PAD;
    int sub = lane >> 4;   // edge subset 0..3
    int fl = lane & 15;    // 16B feature chunk
    float s[8];
#pragma unroll
    for (int i = 0; i < 8; ++i) s[i] = 0.f;

    int idx = csr16[(size_t)node * PAD + lane];  // padded bucket: always in-bounds
    int cm1 = c - 1;
    for (int e = 0; e < c; e += 32) {
        int e0 = e + sub, e1 = e + 4 + sub, e2 = e + 8 + sub, e3 = e + 12 + sub;
        int e4 = e + 16 + sub, e5 = e + 20 + sub, e6 = e + 24 + sub, e7 = e + 28 + sub;
        int a0 = __shfl(idx, imin(e0, cm1));
        int a1 = __shfl(idx, imin(e1, cm1));
        int a2 = __shfl(idx, imin(e2, cm1));
        int a3 = __shfl(idx, imin(e3, cm1));
        int a4 = __shfl(idx, imin(e4, cm1));
        int a5 = __shfl(idx, imin(e5, cm1));
        int a6 = __shfl(idx, imin(e6, cm1));
        int a7 = __shfl(idx, imin(e7, cm1));
        uint4 u0 = P4[(size_t)a0 * 16 + fl];
        uint4 u1 = P4[(size_t)a1 * 16 + fl];
        uint4 u2 = P4[(size_t)a2 * 16 + fl];
        uint4 u3 = P4[(size_t)a3 * 16 + fl];
        uint4 u4 = P4[(size_t)a4 * 16 + fl];
        uint4 u5 = P4[(size_t)a5 * 16 + fl];
        uint4 u6 = P4[(size_t)a6 * 16 + fl];
        uint4 u7 = P4[(size_t)a7 * 16 + fl];
        if (e0 < c) acc8(s, u0);
        if (e1 < c) acc8(s, u1);
        if (e2 < c) acc8(s, u2);
        if (e3 < c) acc8(s, u3);
        if (e4 < c) acc8(s, u4);
        if (e5 < c) acc8(s, u5);
        if (e6 < c) acc8(s, u6);
        if (e7 < c) acc8(s, u7);
    }
    // reduce across the 4 edge-subsets (lanes differing in bits 4,5)
#pragma unroll
    for (int i = 0; i < 8; ++i) s[i] += __shfl_xor(s[i], 16);
#pragma unroll
    for (int i = 0; i < 8; ++i) s[i] += __shfl_xor(s[i], 32);

    if (sub == 0) {
        float ic = 1.0f / (float)(c > 0 ? c : 1);
        uint4 su = S4[(size_t)node * 16 + fl];
        float4 bA = *(const float4*)&b1[fl * 8];
        float4 bB = *(const float4*)&b1[fl * 8 + 4];
        float sv[8];
        sv[0] = bf_lo(su.x); sv[1] = bf_hi(su.x);
        sv[2] = bf_lo(su.y); sv[3] = bf_hi(su.y);
        sv[4] = bf_lo(su.z); sv[5] = bf_hi(su.z);
        sv[6] = bf_lo(su.w); sv[7] = bf_hi(su.w);
        float bb[8] = {bA.x, bA.y, bA.z, bA.w, bB.x, bB.y, bB.z, bB.w};
        float v[8];
#pragma unroll
        for (int i = 0; i < 8; ++i) v[i] = fmaxf(fmaf(s[i], ic, bb[i] + sv[i]), 0.f);
        uint4 o;
        o.x = (uint32)f2bf(v[0]) | ((uint32)f2bf(v[1]) << 16);
        o.y = (uint32)f2bf(v[2]) | ((uint32)f2bf(v[3]) << 16);
        o.z = (uint32)f2bf(v[4]) | ((uint32)f2bf(v[5]) << 16);
        o.w = (uint32)f2bf(v[6]) | ((uint32)f2bf(v[7]) << 16);
        hbf4[(size_t)node * 16 + fl] = o;
    }
}

// ---------------- layer-2 aggregation: one wave per node, 4-deep uint4 gathers --------
// P4: T2l [N][8] uint4 (64 bf16). selfR2: fp32 [N][64]. out: fp32 [N][64].
__global__ __launch_bounds__(256) void agg2_kernel(const uint4* __restrict__ P4,
                                                   const float* __restrict__ selfR2,
                                                   const int* __restrict__ cnt,
                                                   const unsigned short* __restrict__ csr16,
                                                   const float* __restrict__ b2,
                                                   float* __restrict__ out) {
    int wave = threadIdx.x >> 6, lane = threadIdx.x & 63;
    int node = blockIdx.x * 4 + wave;
    if (node >= NNODES) return;
    int c = cnt[node];
    if (c > PAD) c = PAD;
    int sub = lane >> 3;  // edge subset 0..7
    int fl = lane & 7;    // 16B feature chunk
    float s[8];
#pragma unroll
    for (int i = 0; i < 8; ++i) s[i] = 0.f;

    int idx = csr16[(size_t)node * PAD + lane];  // padded bucket: always in-bounds
    int cm1 = c - 1;
    for (int e = 0; e < c; e += 32) {
        int e0 = e + sub, e1 = e + 8 + sub, e2 = e + 16 + sub, e3 = e + 24 + sub;
        int a0 = __shfl(idx, imin(e0, cm1));
        int a1 = __shfl(idx, imin(e1, cm1));
        int a2 = __shfl(idx, imin(e2, cm1));
        int a3 = __shfl(idx, imin(e3, cm1));
        uint4 u0 = P4[(size_t)a0 * 8 + fl];
        uint4 u1 = P4[(size_t)a1 * 8 + fl];
        uint4 u2 = P4[(size_t)a2 * 8 + fl];
        uint4 u3 = P4[(size_t)a3 * 8 + fl];
        if (e0 < c) acc8(s, u0);
        if (e1 < c) acc8(s, u1);
        if (e2 < c) acc8(s, u2);
        if (e3 < c) acc8(s, u3);
    }
#pragma unroll
    for (int i = 0; i < 8; ++i) s[i] += __shfl_xor(s[i], 8);
#pragma unroll
    for (int i = 0; i < 8; ++i) s[i] += __shfl_xor(s[i], 16);
#pragma unroll
    for (int i = 0; i < 8; ++i) s[i] += __shfl_xor(s[i], 32);

    if (sub == 0) {
        float ic = 1.0f / (float)(c > 0 ? c : 1);
        float4 sA = *(const float4*)&selfR2[(size_t)node * 64 + fl * 8];
        float4 sB = *(const float4*)&selfR2[(size_t)node * 64 + fl * 8 + 4];
        float4 bA = *(const float4*)&b2[fl * 8];
        float4 bB = *(const float4*)&b2[fl * 8 + 4];
        float sv[8] = {sA.x, sA.y, sA.z, sA.w, sB.x, sB.y, sB.z, sB.w};
        float bb[8] = {bA.x, bA.y, bA.z, bA.w, bB.x, bB.y, bB.z, bB.w};
        float v[8];
#pragma unroll
        for (int i = 0; i < 8; ++i) v[i] = fmaf(s[i], ic, bb[i] + sv[i]);
        float4 o0 = make_float4(v[0], v[1], v[2], v[3]);
        float4 o1 = make_float4(v[4], v[5], v[6], v[7]);
        *(float4*)&out[(size_t)node * 64 + fl * 8] = o0;
        *(float4*)&out[(size_t)node * 64 + fl * 8 + 4] = o1;
    }
}

extern "C" void kernel_launch(void* const* d_in, const int* in_sizes, int n_in,
                              void* d_out, int out_size, void* d_ws, size_t ws_size,
                              hipStream_t stream) {
    const float* x   = (const float*)d_in[0];
    const void*  ei  = d_in[1];
    const float* W1l = (const float*)d_in[2];
    const float* b1  = (const float*)d_in[3];
    const float* W1r = (const float*)d_in[4];
    const float* W2l = (const float*)d_in[5];
    const float* b2  = (const float*)d_in[6];
    const float* W2r = (const float*)d_in[7];
    float* out = (float*)d_out;

    char* p = (char*)d_ws;
    auto alloc = [&](size_t bytes) {
        char* r = p;
        p += (bytes + 255) & ~(size_t)255;
        return r;
    };
    int*            flag    = (int*)alloc(4);
    int*            cnt     = (int*)alloc(NNODES * 4);
    int*            gcur    = (int*)alloc(NBK * 4);
    int*            bstream = (int*)alloc((size_t)NBK * BCAP * 4);        // 5.24 MB
    unsigned short* csr16   = (unsigned short*)alloc((size_t)NNODES * PAD * 2);  // 5.12 MB
    ushort16*       Wfrag1  = (ushort16*)alloc(32768 * 2);
    ushort16*       Wfrag2  = (ushort16*)alloc(16384 * 2);
    ushort16*       T1l     = (ushort16*)alloc((size_t)NNODES * 128 * 2); // bf16 payload
    ushort16*       T1r     = (ushort16*)alloc((size_t)NNODES * 128 * 2); // bf16 self
    uint32*         hbf     = (uint32*)alloc((size_t)NNODES * 64 * 4);    // h bf16
    ushort16*       T2l     = (ushort16*)alloc((size_t)NNODES * 64 * 2);
    float*          T2r     = (float*)alloc((size_t)NNODES * 64 * 4);

    // pack + flag + gcur zero (x conversion eliminated — gemm1 reads fp32 directly)
    prep_kernel<<<192, 256, 0, stream>>>(gcur, W1l, W1r, W2l, W2r, Wfrag1, Wfrag2,
                                         (const int*)ei, flag);
    // radix CSR build: partition into bucket streams, then LDS regroup -> ushort CSR
    buildA_kernel<<<NBK, 256, 0, stream>>>(ei, flag, gcur, bstream);
    buildB_kernel<<<NBK, 256, 0, stream>>>(bstream, gcur, cnt, csr16);

    // layer 1: T1 = bf16(x) @ [W1l | W1r]; fp32 A read + in-register convert
    gemm1_kernel<<<dim3(NNODES / 64, 2), 256, 0, stream>>>(x, (const uint4*)Wfrag1, T1l, T1r);
    agg1_kernel<<<(NNODES + 3) / 4, 256, 0, stream>>>((const uint4*)T1l, (const uint4*)T1r,
                                                      cnt, csr16, b1, (uint4*)hbf);

    // layer 2: T2 = hbf @ [W2l | W2r]; left 64 -> bf16 payload, right 64 -> fp32 self
    gemm_mfma_kernel<<<dim3(NNODES / 64, 1), 256, 0, stream>>>(
        (const ushort16*)hbf, (const uint4*)Wfrag2, 64, 64, T2l, T2r);
    agg2_kernel<<<(NNODES + 3) / 4, 256, 0, stream>>>((const uint4*)T2l, T2r, cnt, csr16, b2,
                                                      out);
}